// Round 1
// baseline (143.498 us; speedup 1.0000x reference)
//
#include <hip/hip_runtime.h>

// Encoder block: B=128, S=512, D=24, H=4, HD=6, DFF=48, fp32.
// ws layout: Q | K | V | Oattn, each B*H*S*HD floats (25.2 MB total).

#define DD   24
#define HH   4
#define HDD  6
#define DFFN 48
#define SS   512
#define BB   128
#define NTOK (BB*SS)   // 65536
#define NBH  (BB*HH)   // 512

static constexpr float EPSV   = 1e-5f;
// fold 1/sqrt(6) (softmax scale) and log2(e) (exp->exp2) into Q
static constexpr float QSCALE = (float)(1.4426950408889634 / 2.449489742783178);

// ---------------- Kernel A: QKV projection ----------------
__global__ __launch_bounds__(256) void qkv_kernel(
    const float* __restrict__ x,  const float* __restrict__ Wq,
    const float* __restrict__ Wk, const float* __restrict__ Wv,
    float* __restrict__ Q, float* __restrict__ K, float* __restrict__ V)
{
    int t = blockIdx.x * 256 + threadIdx.x;        // token id
    float xv[DD];
    const float4* xp = (const float4*)(x + (size_t)t * DD);
#pragma unroll
    for (int i = 0; i < DD/4; ++i) {
        float4 v = xp[i];
        xv[4*i+0] = v.x; xv[4*i+1] = v.y; xv[4*i+2] = v.z; xv[4*i+3] = v.w;
    }
    int b = t >> 9, s = t & 511;
#pragma unroll
    for (int h = 0; h < HH; ++h) {
        float q[HDD], k[HDD], v[HDD];
#pragma unroll
        for (int d = 0; d < HDD; ++d) {
            int o = h*HDD + d;
            float aq = 0.f, ak = 0.f, av = 0.f;
#pragma unroll
            for (int i = 0; i < DD; ++i) {
                aq = fmaf(xv[i], Wq[o*DD + i], aq);
                ak = fmaf(xv[i], Wk[o*DD + i], ak);
                av = fmaf(xv[i], Wv[o*DD + i], av);
            }
            q[d] = aq * QSCALE; k[d] = ak; v[d] = av;
        }
        size_t base = ((size_t)(b*HH + h)*SS + s) * HDD;
#pragma unroll
        for (int d = 0; d < HDD; d += 2) {
            *(float2*)(Q + base + d) = make_float2(q[d], q[d+1]);
            *(float2*)(K + base + d) = make_float2(k[d], k[d+1]);
            *(float2*)(V + base + d) = make_float2(v[d], v[d+1]);
        }
    }
}

// ---------------- Kernel B: attention per (b,h) ----------------
__global__ __launch_bounds__(256) void attn_kernel(
    const float* __restrict__ Q, const float* __restrict__ K,
    const float* __restrict__ V, float* __restrict__ Oa)
{
    __shared__ float Ks[SS][8];   // stride-8 pad: float4-aligned rows
    __shared__ float Vs[SS][8];
    int bh = blockIdx.x;
    const float* Kp = K + (size_t)bh * SS * HDD;
    const float* Vp = V + (size_t)bh * SS * HDD;
    for (int i = threadIdx.x; i < SS*HDD; i += 256) {
        int r = i / HDD, c = i - r*HDD;
        Ks[r][c] = Kp[i];
        Vs[r][c] = Vp[i];
    }
    __syncthreads();

    const float* Qp = Q + (size_t)bh * SS * HDD;
    int r0 = threadIdx.x, r1 = threadIdx.x + 256;
    float q0[HDD], q1[HDD];
#pragma unroll
    for (int d = 0; d < HDD; d += 2) {
        float2 a = *(const float2*)(Qp + r0*HDD + d); q0[d] = a.x; q0[d+1] = a.y;
        float2 c = *(const float2*)(Qp + r1*HDD + d); q1[d] = c.x; q1[d+1] = c.y;
    }
    float o0[HDD] = {0,0,0,0,0,0}, o1[HDD] = {0,0,0,0,0,0};
    float sum0 = 0.f, sum1 = 0.f;
#pragma unroll 4
    for (int j = 0; j < SS; ++j) {
        float4 ka = *(const float4*)&Ks[j][0];
        float2 kb = *(const float2*)&Ks[j][4];
        float s0 = q0[0]*ka.x; s0 = fmaf(q0[1],ka.y,s0); s0 = fmaf(q0[2],ka.z,s0);
        s0 = fmaf(q0[3],ka.w,s0); s0 = fmaf(q0[4],kb.x,s0); s0 = fmaf(q0[5],kb.y,s0);
        float s1 = q1[0]*ka.x; s1 = fmaf(q1[1],ka.y,s1); s1 = fmaf(q1[2],ka.z,s1);
        s1 = fmaf(q1[3],ka.w,s1); s1 = fmaf(q1[4],kb.x,s1); s1 = fmaf(q1[5],kb.y,s1);
        float p0 = exp2f(s0);   // Q pre-scaled by log2e/sqrt(6); no max-subtract
        float p1 = exp2f(s1);   // (|exponent| <~ 12, safe in fp32)
        sum0 += p0; sum1 += p1;
        float4 va = *(const float4*)&Vs[j][0];
        float2 vb = *(const float2*)&Vs[j][4];
        o0[0]=fmaf(p0,va.x,o0[0]); o0[1]=fmaf(p0,va.y,o0[1]); o0[2]=fmaf(p0,va.z,o0[2]);
        o0[3]=fmaf(p0,va.w,o0[3]); o0[4]=fmaf(p0,vb.x,o0[4]); o0[5]=fmaf(p0,vb.y,o0[5]);
        o1[0]=fmaf(p1,va.x,o1[0]); o1[1]=fmaf(p1,va.y,o1[1]); o1[2]=fmaf(p1,va.z,o1[2]);
        o1[3]=fmaf(p1,va.w,o1[3]); o1[4]=fmaf(p1,vb.x,o1[4]); o1[5]=fmaf(p1,vb.y,o1[5]);
    }
    int b = bh >> 2, h = bh & 3;
    float inv0 = 1.0f / sum0, inv1 = 1.0f / sum1;
    float* op0 = Oa + ((size_t)(b*SS + r0))*DD + h*HDD;
    float* op1 = Oa + ((size_t)(b*SS + r1))*DD + h*HDD;
#pragma unroll
    for (int d = 0; d < HDD; d += 2) {
        *(float2*)(op0 + d) = make_float2(o0[d]*inv0, o0[d+1]*inv0);
        *(float2*)(op1 + d) = make_float2(o1[d]*inv1, o1[d+1]*inv1);
    }
}

// ------- Kernel C: out-proj + add&LN1 + FFN(2xrelu) + add&LN2 -------
__global__ __launch_bounds__(256) void ffn_kernel(
    const float* __restrict__ x,  const float* __restrict__ Oa,
    const float* __restrict__ Wo, const float* __restrict__ W1,
    const float* __restrict__ W2,
    const float* __restrict__ g1, const float* __restrict__ b1,
    const float* __restrict__ g2, const float* __restrict__ b2,
    float* __restrict__ out)
{
    int t = blockIdx.x * 256 + threadIdx.x;
    float xv[DD], ao[DD];
    const float4* xp = (const float4*)(x  + (size_t)t * DD);
    const float4* op = (const float4*)(Oa + (size_t)t * DD);
#pragma unroll
    for (int i = 0; i < DD/4; ++i) {
        float4 a = xp[i]; float4 c = op[i];
        xv[4*i+0]=a.x; xv[4*i+1]=a.y; xv[4*i+2]=a.z; xv[4*i+3]=a.w;
        ao[4*i+0]=c.x; ao[4*i+1]=c.y; ao[4*i+2]=c.z; ao[4*i+3]=c.w;
    }
    // out-proj + residual
    float x1[DD];
#pragma unroll
    for (int o = 0; o < DD; ++o) {
        float a = 0.f;
#pragma unroll
        for (int i = 0; i < DD; ++i) a = fmaf(ao[i], Wo[o*DD + i], a);
        x1[o] = a + xv[o];
    }
    // LN1
    {
        float mu = 0.f;
#pragma unroll
        for (int i = 0; i < DD; ++i) mu += x1[i];
        mu *= (1.0f/DD);
        float var = 0.f;
#pragma unroll
        for (int i = 0; i < DD; ++i) { float d = x1[i]-mu; var = fmaf(d,d,var); }
        var *= (1.0f/DD);
        float r = rsqrtf(var + EPSV);
#pragma unroll
        for (int i = 0; i < DD; ++i) x1[i] = (x1[i]-mu)*r*g1[i] + b1[i];
    }
    // FFN: relu(relu(x1 @ W1.T) @ W2.T)
    float hbuf[DFFN];
#pragma unroll
    for (int j = 0; j < DFFN; ++j) {
        float a = 0.f;
#pragma unroll
        for (int i = 0; i < DD; ++i) a = fmaf(x1[i], W1[j*DD + i], a);
        hbuf[j] = fmaxf(a, 0.f);
    }
    float f2[DD];
#pragma unroll
    for (int o = 0; o < DD; ++o) {
        float a = 0.f;
#pragma unroll
        for (int j = 0; j < DFFN; ++j) a = fmaf(hbuf[j], W2[o*DFFN + j], a);
        f2[o] = fmaxf(a, 0.f) + x1[o];      // residual
    }
    // LN2
    {
        float mu = 0.f;
#pragma unroll
        for (int i = 0; i < DD; ++i) mu += f2[i];
        mu *= (1.0f/DD);
        float var = 0.f;
#pragma unroll
        for (int i = 0; i < DD; ++i) { float d = f2[i]-mu; var = fmaf(d,d,var); }
        var *= (1.0f/DD);
        float r = rsqrtf(var + EPSV);
#pragma unroll
        for (int i = 0; i < DD; ++i) f2[i] = (f2[i]-mu)*r*g2[i] + b2[i];
    }
    float4* outp = (float4*)(out + (size_t)t * DD);
#pragma unroll
    for (int i = 0; i < DD/4; ++i)
        outp[i] = make_float4(f2[4*i+0], f2[4*i+1], f2[4*i+2], f2[4*i+3]);
}

extern "C" void kernel_launch(void* const* d_in, const int* in_sizes, int n_in,
                              void* d_out, int out_size, void* d_ws, size_t ws_size,
                              hipStream_t stream) {
    const float* x  = (const float*)d_in[0];
    const float* Wq = (const float*)d_in[1];
    const float* Wk = (const float*)d_in[2];
    const float* Wv = (const float*)d_in[3];
    const float* Wo = (const float*)d_in[4];
    const float* W1 = (const float*)d_in[5];
    const float* W2 = (const float*)d_in[6];
    const float* g1 = (const float*)d_in[7];
    const float* b1 = (const float*)d_in[8];
    const float* g2 = (const float*)d_in[9];
    const float* b2 = (const float*)d_in[10];
    float* out = (float*)d_out;

    size_t N = (size_t)NBH * SS * HDD;   // 1,572,864 floats per buffer
    float* Q  = (float*)d_ws;
    float* K  = Q + N;
    float* V  = K + N;
    float* Oa = V + N;

    qkv_kernel<<<NTOK/256, 256, 0, stream>>>(x, Wq, Wk, Wv, Q, K, V);
    attn_kernel<<<NBH, 256, 0, stream>>>(Q, K, V, Oa);
    ffn_kernel<<<NTOK/256, 256, 0, stream>>>(x, Oa, Wo, W1, W2, g1, b1, g2, b2, out);
}

// Round 3
// 94.390 us; speedup vs baseline: 1.5203x; 1.5203x over previous
//
#include <hip/hip_runtime.h>

// Encoder block: B=128, S=512, D=24, H=4, HD=6, DFF=48, fp32 in/out.
// R3: MFMA (32x32x16 bf16) attention, zero-LDS, zero-crosslane.
//  - QK^T: A=K rows, B=Q rows, identical packing -> perm-agnostic.
//  - PV:   P packed in S-register order; V^T pre-swizzled to the SAME
//          (hi,j)->key map K(hi,j)=(j&3)+8*(j>>2)+4*hi -> perm-agnostic.
//  - rowsum: ones-rows at d=6 (hi=1 reads O[2]) and d=8 (hi=0 reads O[4]).
// ws: Qb | Kb (row-major 8 bf16/row) | Vt (swizzled) | Oa (fp32).

#define DD   24
#define HH   4
#define HDD  6
#define DFFN 48
#define SS   512
#define BB   128
#define NTOK (BB*SS)   // 65536
#define NBH  (BB*HH)   // 512

typedef unsigned short ushort_t;
typedef unsigned int   uint_t;
typedef __bf16  bf16x8  __attribute__((ext_vector_type(8)));
typedef float   f32x16  __attribute__((ext_vector_type(16)));

static constexpr float EPSV   = 1e-5f;
// fold 1/sqrt(6) (softmax scale) and log2(e) (exp->exp2) into Q
static constexpr float QSCALE = (float)(1.4426950408889634 / 2.449489742783178);

// Vt geometry: [bh][kt(16)][m(2)][d(9)][hi(2)][j(8)]  (ushort elements)
#define VT_PER_BH (16*2*9*2*8)   // 4608
#define VT_PER_KT (2*9*2*8)      // 576
#define VT_PER_M  (9*2*8)        // 144

__device__ __forceinline__ uint_t cvtpk(float lo, float hi) {
    uint_t r;
    asm("v_cvt_pk_bf16_f32 %0, %1, %2" : "=v"(r) : "v"(lo), "v"(hi));
    return r;
}
__device__ __forceinline__ ushort_t f2bf(float f) {
    return (ushort_t)cvtpk(f, 0.0f);
}

// ---------------- Kernel A: QKV projection -> bf16 Qb/Kb/Vt ----------------
__global__ __launch_bounds__(256) void qkv_kernel(
    const float* __restrict__ x,  const float* __restrict__ Wq,
    const float* __restrict__ Wk, const float* __restrict__ Wv,
    ushort_t* __restrict__ Qb, ushort_t* __restrict__ Kb, ushort_t* __restrict__ Vt)
{
    int t = blockIdx.x * 256 + threadIdx.x;        // token id
    float xv[DD];
    const float4* xp = (const float4*)(x + (size_t)t * DD);
#pragma unroll
    for (int i = 0; i < DD/4; ++i) {
        float4 v = xp[i];
        xv[4*i+0] = v.x; xv[4*i+1] = v.y; xv[4*i+2] = v.z; xv[4*i+3] = v.w;
    }
    int b = t >> 9, s = t & 511;
    // V^T swizzle coordinates for this token (= key position s)
    int kt  = s >> 5;
    int kl  = s & 31;
    int m   = (kl >> 4) & 1;
    int k16 = kl & 15;
    int hi  = (k16 >> 2) & 1;
    int j   = (k16 & 3) + ((k16 >> 3) << 2);
#pragma unroll
    for (int h = 0; h < HH; ++h) {
        float q[HDD], k[HDD], v[HDD];
#pragma unroll
        for (int d = 0; d < HDD; ++d) {
            int o = h*HDD + d;
            float aq = 0.f, ak = 0.f, av = 0.f;
#pragma unroll
            for (int i = 0; i < DD; ++i) {
                aq = fmaf(xv[i], Wq[o*DD + i], aq);
                ak = fmaf(xv[i], Wk[o*DD + i], ak);
                av = fmaf(xv[i], Wv[o*DD + i], av);
            }
            q[d] = aq * QSCALE; k[d] = ak; v[d] = av;
        }
        int bh = b*HH + h;
        // Qb/Kb rows: 8 bf16 (2 zero pad), one 16B store each
        uint4 qs, ks;
        qs.x = cvtpk(q[0], q[1]); qs.y = cvtpk(q[2], q[3]); qs.z = cvtpk(q[4], q[5]); qs.w = 0;
        ks.x = cvtpk(k[0], k[1]); ks.y = cvtpk(k[2], k[3]); ks.z = cvtpk(k[4], k[5]); ks.w = 0;
        *(uint4*)(Qb + ((size_t)bh*SS + s)*8) = qs;
        *(uint4*)(Kb + ((size_t)bh*SS + s)*8) = ks;
        // Vt swizzled scatter: rows d=0..5 = V^T, d=6 ones, d=7 zeros, d=8 ones
        ushort_t* vp = Vt + (size_t)bh*VT_PER_BH + kt*VT_PER_KT + m*VT_PER_M + hi*8 + j;
#pragma unroll
        for (int d = 0; d < HDD; ++d) vp[d*16] = f2bf(v[d]);
        vp[6*16] = 0x3F80u;   // 1.0
        vp[7*16] = 0;
        vp[8*16] = 0x3F80u;   // 1.0
    }
}

// ---------------- Kernel B: MFMA attention ----------------
// block = 256 thr (4 waves), grid (512 bh, 2); each wave: 2 q-tiles of 32 rows.
__global__ __launch_bounds__(256) void attn_kernel(
    const ushort_t* __restrict__ Qb, const ushort_t* __restrict__ Kb,
    const ushort_t* __restrict__ Vt, float* __restrict__ Oa)
{
    int lane = threadIdx.x & 63;
    int wv   = threadIdx.x >> 6;
    int bh = blockIdx.x;
    int b = bh >> 2, h = bh & 3;
    int hi = lane >> 5;
    int c  = lane & 31;

    const ushort_t* Qp = Qb + (size_t)bh*SS*8;
    const ushort_t* Kp = Kb + (size_t)bh*SS*8;
    const ushort_t* Vp = Vt + (size_t)bh*VT_PER_BH + (c*2 + hi)*8;  // + kt*VT_PER_KT + m*VT_PER_M
    bool vld = (c < 9);

    f32x16 Z;
#pragma unroll
    for (int i = 0; i < 16; ++i) Z[i] = 0.f;

#pragma unroll
    for (int ti = 0; ti < 2; ++ti) {
        int tile = blockIdx.y*8 + wv*2 + ti;   // 0..15
        int q0 = tile * 32;
        // B-frag: Q rows as columns (only hi==0 holds real d 0..7)
        uint4 qf = {0,0,0,0};
        if (hi == 0) qf = *(const uint4*)(Qp + ((size_t)(q0 + c))*8);
        bf16x8 bq = __builtin_bit_cast(bf16x8, qf);

        f32x16 O;
#pragma unroll
        for (int i = 0; i < 16; ++i) O[i] = 0.f;

#pragma unroll 2
        for (int kt = 0; kt < 16; ++kt) {
            // A-frag: K tile rows (row=key=c)
            uint4 kf = {0,0,0,0};
            if (hi == 0) kf = *(const uint4*)(Kp + ((size_t)(kt*32 + c))*8);
            f32x16 S = __builtin_amdgcn_mfma_f32_32x32x16_bf16(
                __builtin_bit_cast(bf16x8, kf), bq, Z, 0, 0, 0);
            // S reg r on lane (c,hi) = score(key kt*32+(r&3)+8*(r>>2)+4hi, q=c).
            // P B-frag packed in the SAME (hi,j)->key order: element j = exp2(S[j]).
            uint4 fa, fb;
            fa.x = cvtpk(__builtin_amdgcn_exp2f(S[0]),  __builtin_amdgcn_exp2f(S[1]));
            fa.y = cvtpk(__builtin_amdgcn_exp2f(S[2]),  __builtin_amdgcn_exp2f(S[3]));
            fa.z = cvtpk(__builtin_amdgcn_exp2f(S[4]),  __builtin_amdgcn_exp2f(S[5]));
            fa.w = cvtpk(__builtin_amdgcn_exp2f(S[6]),  __builtin_amdgcn_exp2f(S[7]));
            fb.x = cvtpk(__builtin_amdgcn_exp2f(S[8]),  __builtin_amdgcn_exp2f(S[9]));
            fb.y = cvtpk(__builtin_amdgcn_exp2f(S[10]), __builtin_amdgcn_exp2f(S[11]));
            fb.z = cvtpk(__builtin_amdgcn_exp2f(S[12]), __builtin_amdgcn_exp2f(S[13]));
            fb.w = cvtpk(__builtin_amdgcn_exp2f(S[14]), __builtin_amdgcn_exp2f(S[15]));
            // A-frags: V^T pre-swizzled to the same (hi,j)->key order.
            // rows: 0..5 = V dims, 6 = ones, 7 = zeros, 8 = ones.
            uint4 va = {0,0,0,0}, vb = {0,0,0,0};
            if (vld) {
                const ushort_t* vp = Vp + kt*VT_PER_KT;
                va = *(const uint4*)(vp);
                vb = *(const uint4*)(vp + VT_PER_M);
            }
            O = __builtin_amdgcn_mfma_f32_32x32x16_bf16(
                __builtin_bit_cast(bf16x8, va), __builtin_bit_cast(bf16x8, fa), O, 0, 0, 0);
            O = __builtin_amdgcn_mfma_f32_32x32x16_bf16(
                __builtin_bit_cast(bf16x8, vb), __builtin_bit_cast(bf16x8, fb), O, 0, 0, 0);
        }
        // O^T: lane (q=c,hi), reg r -> d-row = (r&3)+8*(r>>2)+4*hi
        // hi=0: regs 0..3 = d0..3, reg 4 = row8 = rowsum
        // hi=1: regs 0,1 = d4,d5,  reg 2 = row6 = rowsum
        float inv = 1.0f / (hi ? O[2] : O[4]);
        float* op = Oa + ((size_t)b*SS + q0 + c)*DD + h*HDD;
        if (hi == 0) {
            *(float2*)(op + 0) = make_float2(O[0]*inv, O[1]*inv);
            *(float2*)(op + 2) = make_float2(O[2]*inv, O[3]*inv);
        } else {
            *(float2*)(op + 4) = make_float2(O[0]*inv, O[1]*inv);
        }
    }
}

// ------- Kernel C: out-proj + add&LN1 + FFN(2xrelu) + add&LN2 -------
__global__ __launch_bounds__(256) void ffn_kernel(
    const float* __restrict__ x,  const float* __restrict__ Oa,
    const float* __restrict__ Wo, const float* __restrict__ W1,
    const float* __restrict__ W2,
    const float* __restrict__ g1, const float* __restrict__ b1,
    const float* __restrict__ g2, const float* __restrict__ b2,
    float* __restrict__ out)
{
    int t = blockIdx.x * 256 + threadIdx.x;
    float xv[DD], ao[DD];
    const float4* xp = (const float4*)(x  + (size_t)t * DD);
    const float4* op = (const float4*)(Oa + (size_t)t * DD);
#pragma unroll
    for (int i = 0; i < DD/4; ++i) {
        float4 a = xp[i]; float4 c = op[i];
        xv[4*i+0]=a.x; xv[4*i+1]=a.y; xv[4*i+2]=a.z; xv[4*i+3]=a.w;
        ao[4*i+0]=c.x; ao[4*i+1]=c.y; ao[4*i+2]=c.z; ao[4*i+3]=c.w;
    }
    float x1[DD];
#pragma unroll
    for (int o = 0; o < DD; ++o) {
        float a = 0.f;
#pragma unroll
        for (int i = 0; i < DD; ++i) a = fmaf(ao[i], Wo[o*DD + i], a);
        x1[o] = a + xv[o];
    }
    {
        float mu = 0.f;
#pragma unroll
        for (int i = 0; i < DD; ++i) mu += x1[i];
        mu *= (1.0f/DD);
        float var = 0.f;
#pragma unroll
        for (int i = 0; i < DD; ++i) { float d = x1[i]-mu; var = fmaf(d,d,var); }
        var *= (1.0f/DD);
        float r = rsqrtf(var + EPSV);
#pragma unroll
        for (int i = 0; i < DD; ++i) x1[i] = (x1[i]-mu)*r*g1[i] + b1[i];
    }
    float hbuf[DFFN];
#pragma unroll
    for (int jj = 0; jj < DFFN; ++jj) {
        float a = 0.f;
#pragma unroll
        for (int i = 0; i < DD; ++i) a = fmaf(x1[i], W1[jj*DD + i], a);
        hbuf[jj] = fmaxf(a, 0.f);
    }
    float f2[DD];
#pragma unroll
    for (int o = 0; o < DD; ++o) {
        float a = 0.f;
#pragma unroll
        for (int jj = 0; jj < DFFN; ++jj) a = fmaf(hbuf[jj], W2[o*DFFN + jj], a);
        f2[o] = fmaxf(a, 0.f) + x1[o];
    }
    {
        float mu = 0.f;
#pragma unroll
        for (int i = 0; i < DD; ++i) mu += f2[i];
        mu *= (1.0f/DD);
        float var = 0.f;
#pragma unroll
        for (int i = 0; i < DD; ++i) { float d = f2[i]-mu; var = fmaf(d,d,var); }
        var *= (1.0f/DD);
        float r = rsqrtf(var + EPSV);
#pragma unroll
        for (int i = 0; i < DD; ++i) f2[i] = (f2[i]-mu)*r*g2[i] + b2[i];
    }
    float4* outp = (float4*)(out + (size_t)t * DD);
#pragma unroll
    for (int i = 0; i < DD/4; ++i)
        outp[i] = make_float4(f2[4*i+0], f2[4*i+1], f2[4*i+2], f2[4*i+3]);
}

extern "C" void kernel_launch(void* const* d_in, const int* in_sizes, int n_in,
                              void* d_out, int out_size, void* d_ws, size_t ws_size,
                              hipStream_t stream) {
    const float* x  = (const float*)d_in[0];
    const float* Wq = (const float*)d_in[1];
    const float* Wk = (const float*)d_in[2];
    const float* Wv = (const float*)d_in[3];
    const float* Wo = (const float*)d_in[4];
    const float* W1 = (const float*)d_in[5];
    const float* W2 = (const float*)d_in[6];
    const float* g1 = (const float*)d_in[7];
    const float* b1 = (const float*)d_in[8];
    const float* g2 = (const float*)d_in[9];
    const float* b2 = (const float*)d_in[10];
    float* out = (float*)d_out;

    size_t N8 = (size_t)NBH * SS * 8;         // 2,097,152 ushorts (Qb, Kb)
    size_t NV = (size_t)NBH * VT_PER_BH;      // 2,359,296 ushorts (Vt)
    ushort_t* Qb = (ushort_t*)d_ws;
    ushort_t* Kb = Qb + N8;
    ushort_t* Vt = Kb + N8;
    float*    Oa = (float*)(Vt + NV);

    qkv_kernel<<<NTOK/256, 256, 0, stream>>>(x, Wq, Wk, Wv, Qb, Kb, Vt);
    attn_kernel<<<dim3(NBH, 2), 256, 0, stream>>>(Qb, Kb, Vt, Oa);
    ffn_kernel<<<NTOK/256, 256, 0, stream>>>(x, Oa, Wo, W1, W2, g1, b1, g2, b2, out);
}

// Round 4
// 83.569 us; speedup vs baseline: 1.7171x; 1.1295x over previous
//
#include <hip/hip_runtime.h>

// Encoder block: B=128, S=512, D=24, H=4, HD=6, DFF=48, fp32 in/out.
// R4: R3 + LDS weight staging in qkv/ffn (kills s_load latency stalls).
// Attention: MFMA 32x32x16 bf16, zero-LDS, perm-agnostic packing (unchanged).

#define DD   24
#define HH   4
#define HDD  6
#define DFFN 48
#define SS   512
#define BB   128
#define NTOK (BB*SS)   // 65536
#define NBH  (BB*HH)   // 512

typedef unsigned short ushort_t;
typedef unsigned int   uint_t;
typedef __bf16  bf16x8  __attribute__((ext_vector_type(8)));
typedef float   f32x16  __attribute__((ext_vector_type(16)));

static constexpr float EPSV   = 1e-5f;
static constexpr float QSCALE = (float)(1.4426950408889634 / 2.449489742783178);

// Vt geometry: [bh][kt(16)][m(2)][d(9)][hi(2)][j(8)]  (ushort elements)
#define VT_PER_BH (16*2*9*2*8)   // 4608
#define VT_PER_KT (2*9*2*8)      // 576
#define VT_PER_M  (9*2*8)        // 144

__device__ __forceinline__ uint_t cvtpk(float lo, float hi) {
    uint_t r;
    asm("v_cvt_pk_bf16_f32 %0, %1, %2" : "=v"(r) : "v"(lo), "v"(hi));
    return r;
}
__device__ __forceinline__ ushort_t f2bf(float f) {
    return (ushort_t)cvtpk(f, 0.0f);
}

// ---------------- Kernel A: QKV projection -> bf16 Qb/Kb/Vt ----------------
__global__ __launch_bounds__(256) void qkv_kernel(
    const float* __restrict__ x,  const float* __restrict__ Wq,
    const float* __restrict__ Wk, const float* __restrict__ Wv,
    ushort_t* __restrict__ Qb, ushort_t* __restrict__ Kb, ushort_t* __restrict__ Vt)
{
    __shared__ float sWq[DD*DD], sWk[DD*DD], sWv[DD*DD];
    for (int i = threadIdx.x; i < DD*DD; i += 256) {
        sWq[i] = Wq[i]; sWk[i] = Wk[i]; sWv[i] = Wv[i];
    }
    __syncthreads();

    int t = blockIdx.x * 256 + threadIdx.x;        // token id
    float xv[DD];
    const float4* xp = (const float4*)(x + (size_t)t * DD);
#pragma unroll
    for (int i = 0; i < DD/4; ++i) {
        float4 v = xp[i];
        xv[4*i+0] = v.x; xv[4*i+1] = v.y; xv[4*i+2] = v.z; xv[4*i+3] = v.w;
    }
    int b = t >> 9, s = t & 511;
    // V^T swizzle coordinates for this token (= key position s)
    int kt  = s >> 5;
    int kl  = s & 31;
    int m   = (kl >> 4) & 1;
    int k16 = kl & 15;
    int hi  = (k16 >> 2) & 1;
    int j   = (k16 & 3) + ((k16 >> 3) << 2);
#pragma unroll
    for (int h = 0; h < HH; ++h) {
        float q[HDD], k[HDD], v[HDD];
#pragma unroll
        for (int d = 0; d < HDD; ++d) {
            int o = h*HDD + d;
            float aq = 0.f, ak = 0.f, av = 0.f;
#pragma unroll
            for (int i = 0; i < DD; ++i) {
                aq = fmaf(xv[i], sWq[o*DD + i], aq);
                ak = fmaf(xv[i], sWk[o*DD + i], ak);
                av = fmaf(xv[i], sWv[o*DD + i], av);
            }
            q[d] = aq * QSCALE; k[d] = ak; v[d] = av;
        }
        int bh = b*HH + h;
        uint4 qs, ks;
        qs.x = cvtpk(q[0], q[1]); qs.y = cvtpk(q[2], q[3]); qs.z = cvtpk(q[4], q[5]); qs.w = 0;
        ks.x = cvtpk(k[0], k[1]); ks.y = cvtpk(k[2], k[3]); ks.z = cvtpk(k[4], k[5]); ks.w = 0;
        *(uint4*)(Qb + ((size_t)bh*SS + s)*8) = qs;
        *(uint4*)(Kb + ((size_t)bh*SS + s)*8) = ks;
        // Vt swizzled scatter: rows d=0..5 = V^T, d=6 ones, d=7 zeros, d=8 ones
        ushort_t* vp = Vt + (size_t)bh*VT_PER_BH + kt*VT_PER_KT + m*VT_PER_M + hi*8 + j;
#pragma unroll
        for (int d = 0; d < HDD; ++d) vp[d*16] = f2bf(v[d]);
        vp[6*16] = 0x3F80u;   // 1.0
        vp[7*16] = 0;
        vp[8*16] = 0x3F80u;   // 1.0
    }
}

// ---------------- Kernel B: MFMA attention (unchanged from R3) ----------------
__global__ __launch_bounds__(256) void attn_kernel(
    const ushort_t* __restrict__ Qb, const ushort_t* __restrict__ Kb,
    const ushort_t* __restrict__ Vt, float* __restrict__ Oa)
{
    int lane = threadIdx.x & 63;
    int wv   = threadIdx.x >> 6;
    int bh = blockIdx.x;
    int b = bh >> 2, h = bh & 3;
    int hi = lane >> 5;
    int c  = lane & 31;

    const ushort_t* Qp = Qb + (size_t)bh*SS*8;
    const ushort_t* Kp = Kb + (size_t)bh*SS*8;
    const ushort_t* Vp = Vt + (size_t)bh*VT_PER_BH + (c*2 + hi)*8;
    bool vld = (c < 9);

    f32x16 Z;
#pragma unroll
    for (int i = 0; i < 16; ++i) Z[i] = 0.f;

#pragma unroll
    for (int ti = 0; ti < 2; ++ti) {
        int tile = blockIdx.y*8 + wv*2 + ti;   // 0..15
        int q0 = tile * 32;
        uint4 qf = {0,0,0,0};
        if (hi == 0) qf = *(const uint4*)(Qp + ((size_t)(q0 + c))*8);
        bf16x8 bq = __builtin_bit_cast(bf16x8, qf);

        f32x16 O;
#pragma unroll
        for (int i = 0; i < 16; ++i) O[i] = 0.f;

#pragma unroll 2
        for (int kt = 0; kt < 16; ++kt) {
            uint4 kf = {0,0,0,0};
            if (hi == 0) kf = *(const uint4*)(Kp + ((size_t)(kt*32 + c))*8);
            f32x16 S = __builtin_amdgcn_mfma_f32_32x32x16_bf16(
                __builtin_bit_cast(bf16x8, kf), bq, Z, 0, 0, 0);
            uint4 fa, fb;
            fa.x = cvtpk(__builtin_amdgcn_exp2f(S[0]),  __builtin_amdgcn_exp2f(S[1]));
            fa.y = cvtpk(__builtin_amdgcn_exp2f(S[2]),  __builtin_amdgcn_exp2f(S[3]));
            fa.z = cvtpk(__builtin_amdgcn_exp2f(S[4]),  __builtin_amdgcn_exp2f(S[5]));
            fa.w = cvtpk(__builtin_amdgcn_exp2f(S[6]),  __builtin_amdgcn_exp2f(S[7]));
            fb.x = cvtpk(__builtin_amdgcn_exp2f(S[8]),  __builtin_amdgcn_exp2f(S[9]));
            fb.y = cvtpk(__builtin_amdgcn_exp2f(S[10]), __builtin_amdgcn_exp2f(S[11]));
            fb.z = cvtpk(__builtin_amdgcn_exp2f(S[12]), __builtin_amdgcn_exp2f(S[13]));
            fb.w = cvtpk(__builtin_amdgcn_exp2f(S[14]), __builtin_amdgcn_exp2f(S[15]));
            uint4 va = {0,0,0,0}, vb = {0,0,0,0};
            if (vld) {
                const ushort_t* vp = Vp + kt*VT_PER_KT;
                va = *(const uint4*)(vp);
                vb = *(const uint4*)(vp + VT_PER_M);
            }
            O = __builtin_amdgcn_mfma_f32_32x32x16_bf16(
                __builtin_bit_cast(bf16x8, va), __builtin_bit_cast(bf16x8, fa), O, 0, 0, 0);
            O = __builtin_amdgcn_mfma_f32_32x32x16_bf16(
                __builtin_bit_cast(bf16x8, vb), __builtin_bit_cast(bf16x8, fb), O, 0, 0, 0);
        }
        float inv = 1.0f / (hi ? O[2] : O[4]);
        float* op = Oa + ((size_t)b*SS + q0 + c)*DD + h*HDD;
        if (hi == 0) {
            *(float2*)(op + 0) = make_float2(O[0]*inv, O[1]*inv);
            *(float2*)(op + 2) = make_float2(O[2]*inv, O[3]*inv);
        } else {
            *(float2*)(op + 4) = make_float2(O[0]*inv, O[1]*inv);
        }
    }
}

// ------- Kernel C: out-proj + add&LN1 + FFN(2xrelu) + add&LN2 -------
__global__ __launch_bounds__(256) void ffn_kernel(
    const float* __restrict__ x,  const float* __restrict__ Oa,
    const float* __restrict__ Wo, const float* __restrict__ W1,
    const float* __restrict__ W2,
    const float* __restrict__ g1, const float* __restrict__ b1,
    const float* __restrict__ g2, const float* __restrict__ b2,
    float* __restrict__ out)
{
    __shared__ float sWo[DD*DD], sW1[DFFN*DD], sW2[DD*DFFN];
    __shared__ float sg1[DD], sb1[DD], sg2[DD], sb2[DD];
    for (int i = threadIdx.x; i < DD*DD; i += 256) sWo[i] = Wo[i];
    for (int i = threadIdx.x; i < DFFN*DD; i += 256) sW1[i] = W1[i];
    for (int i = threadIdx.x; i < DD*DFFN; i += 256) sW2[i] = W2[i];
    if (threadIdx.x < DD) {
        sg1[threadIdx.x] = g1[threadIdx.x];
        sb1[threadIdx.x] = b1[threadIdx.x];
        sg2[threadIdx.x] = g2[threadIdx.x];
        sb2[threadIdx.x] = b2[threadIdx.x];
    }
    __syncthreads();

    int t = blockIdx.x * 256 + threadIdx.x;
    float xv[DD], ao[DD];
    const float4* xp = (const float4*)(x  + (size_t)t * DD);
    const float4* op = (const float4*)(Oa + (size_t)t * DD);
#pragma unroll
    for (int i = 0; i < DD/4; ++i) {
        float4 a = xp[i]; float4 c = op[i];
        xv[4*i+0]=a.x; xv[4*i+1]=a.y; xv[4*i+2]=a.z; xv[4*i+3]=a.w;
        ao[4*i+0]=c.x; ao[4*i+1]=c.y; ao[4*i+2]=c.z; ao[4*i+3]=c.w;
    }
    float x1[DD];
#pragma unroll
    for (int o = 0; o < DD; ++o) {
        float a = 0.f;
#pragma unroll
        for (int i = 0; i < DD; ++i) a = fmaf(ao[i], sWo[o*DD + i], a);
        x1[o] = a + xv[o];
    }
    {
        float mu = 0.f;
#pragma unroll
        for (int i = 0; i < DD; ++i) mu += x1[i];
        mu *= (1.0f/DD);
        float var = 0.f;
#pragma unroll
        for (int i = 0; i < DD; ++i) { float d = x1[i]-mu; var = fmaf(d,d,var); }
        var *= (1.0f/DD);
        float r = rsqrtf(var + EPSV);
#pragma unroll
        for (int i = 0; i < DD; ++i) x1[i] = (x1[i]-mu)*r*sg1[i] + sb1[i];
    }
    float hbuf[DFFN];
#pragma unroll
    for (int jj = 0; jj < DFFN; ++jj) {
        float a = 0.f;
#pragma unroll
        for (int i = 0; i < DD; ++i) a = fmaf(x1[i], sW1[jj*DD + i], a);
        hbuf[jj] = fmaxf(a, 0.f);
    }
    float f2[DD];
#pragma unroll
    for (int o = 0; o < DD; ++o) {
        float a = 0.f;
#pragma unroll
        for (int jj = 0; jj < DFFN; ++jj) a = fmaf(hbuf[jj], sW2[o*DFFN + jj], a);
        f2[o] = fmaxf(a, 0.f) + x1[o];
    }
    {
        float mu = 0.f;
#pragma unroll
        for (int i = 0; i < DD; ++i) mu += f2[i];
        mu *= (1.0f/DD);
        float var = 0.f;
#pragma unroll
        for (int i = 0; i < DD; ++i) { float d = f2[i]-mu; var = fmaf(d,d,var); }
        var *= (1.0f/DD);
        float r = rsqrtf(var + EPSV);
#pragma unroll
        for (int i = 0; i < DD; ++i) f2[i] = (f2[i]-mu)*r*sg2[i] + sb2[i];
    }
    float4* outp = (float4*)(out + (size_t)t * DD);
#pragma unroll
    for (int i = 0; i < DD/4; ++i)
        outp[i] = make_float4(f2[4*i+0], f2[4*i+1], f2[4*i+2], f2[4*i+3]);
}

extern "C" void kernel_launch(void* const* d_in, const int* in_sizes, int n_in,
                              void* d_out, int out_size, void* d_ws, size_t ws_size,
                              hipStream_t stream) {
    const float* x  = (const float*)d_in[0];
    const float* Wq = (const float*)d_in[1];
    const float* Wk = (const float*)d_in[2];
    const float* Wv = (const float*)d_in[3];
    const float* Wo = (const float*)d_in[4];
    const float* W1 = (const float*)d_in[5];
    const float* W2 = (const float*)d_in[6];
    const float* g1 = (const float*)d_in[7];
    const float* b1 = (const float*)d_in[8];
    const float* g2 = (const float*)d_in[9];
    const float* b2 = (const float*)d_in[10];
    float* out = (float*)d_out;

    size_t N8 = (size_t)NBH * SS * 8;         // Qb, Kb
    size_t NV = (size_t)NBH * VT_PER_BH;      // Vt
    ushort_t* Qb = (ushort_t*)d_ws;
    ushort_t* Kb = Qb + N8;
    ushort_t* Vt = Kb + N8;
    float*    Oa = (float*)(Vt + NV);

    qkv_kernel<<<NTOK/256, 256, 0, stream>>>(x, Wq, Wk, Wv, Qb, Kb, Vt);
    attn_kernel<<<dim3(NBH, 2), 256, 0, stream>>>(Qb, Kb, Vt, Oa);
    ffn_kernel<<<NTOK/256, 256, 0, stream>>>(x, Oa, Wo, W1, W2, g1, b1, g2, b2, out);
}

// Round 5
// 83.548 us; speedup vs baseline: 1.7175x; 1.0002x over previous
//
#include <hip/hip_runtime.h>

// Encoder block: B=128, S=512, D=24, H=4, HD=6, DFF=48, fp32 in/out.
// R5: R4 + __launch_bounds__(256,1) on qkv/ffn — the per-thread unrolled
// arrays (~110 live floats in ffn) were scratch-spilling at VGPR_Count=40.
// Attention: MFMA 32x32x16 bf16, zero-LDS, perm-agnostic packing (unchanged).

#define DD   24
#define HH   4
#define HDD  6
#define DFFN 48
#define SS   512
#define BB   128
#define NTOK (BB*SS)   // 65536
#define NBH  (BB*HH)   // 512

typedef unsigned short ushort_t;
typedef unsigned int   uint_t;
typedef __bf16  bf16x8  __attribute__((ext_vector_type(8)));
typedef float   f32x16  __attribute__((ext_vector_type(16)));

static constexpr float EPSV   = 1e-5f;
static constexpr float QSCALE = (float)(1.4426950408889634 / 2.449489742783178);

// Vt geometry: [bh][kt(16)][m(2)][d(9)][hi(2)][j(8)]  (ushort elements)
#define VT_PER_BH (16*2*9*2*8)   // 4608
#define VT_PER_KT (2*9*2*8)      // 576
#define VT_PER_M  (9*2*8)        // 144

__device__ __forceinline__ uint_t cvtpk(float lo, float hi) {
    uint_t r;
    asm("v_cvt_pk_bf16_f32 %0, %1, %2" : "=v"(r) : "v"(lo), "v"(hi));
    return r;
}
__device__ __forceinline__ ushort_t f2bf(float f) {
    return (ushort_t)cvtpk(f, 0.0f);
}

// ---------------- Kernel A: QKV projection -> bf16 Qb/Kb/Vt ----------------
__global__ __launch_bounds__(256, 1) void qkv_kernel(
    const float* __restrict__ x,  const float* __restrict__ Wq,
    const float* __restrict__ Wk, const float* __restrict__ Wv,
    ushort_t* __restrict__ Qb, ushort_t* __restrict__ Kb, ushort_t* __restrict__ Vt)
{
    __shared__ float sWq[DD*DD], sWk[DD*DD], sWv[DD*DD];
    for (int i = threadIdx.x; i < DD*DD; i += 256) {
        sWq[i] = Wq[i]; sWk[i] = Wk[i]; sWv[i] = Wv[i];
    }
    __syncthreads();

    int t = blockIdx.x * 256 + threadIdx.x;        // token id
    float xv[DD];
    const float4* xp = (const float4*)(x + (size_t)t * DD);
#pragma unroll
    for (int i = 0; i < DD/4; ++i) {
        float4 v = xp[i];
        xv[4*i+0] = v.x; xv[4*i+1] = v.y; xv[4*i+2] = v.z; xv[4*i+3] = v.w;
    }
    int b = t >> 9, s = t & 511;
    // V^T swizzle coordinates for this token (= key position s)
    int kt  = s >> 5;
    int kl  = s & 31;
    int m   = (kl >> 4) & 1;
    int k16 = kl & 15;
    int hi  = (k16 >> 2) & 1;
    int j   = (k16 & 3) + ((k16 >> 3) << 2);
#pragma unroll
    for (int h = 0; h < HH; ++h) {
        float q[HDD], k[HDD], v[HDD];
#pragma unroll
        for (int d = 0; d < HDD; ++d) {
            int o = h*HDD + d;
            float aq = 0.f, ak = 0.f, av = 0.f;
#pragma unroll
            for (int i = 0; i < DD; ++i) {
                aq = fmaf(xv[i], sWq[o*DD + i], aq);
                ak = fmaf(xv[i], sWk[o*DD + i], ak);
                av = fmaf(xv[i], sWv[o*DD + i], av);
            }
            q[d] = aq * QSCALE; k[d] = ak; v[d] = av;
        }
        int bh = b*HH + h;
        uint4 qs, ks;
        qs.x = cvtpk(q[0], q[1]); qs.y = cvtpk(q[2], q[3]); qs.z = cvtpk(q[4], q[5]); qs.w = 0;
        ks.x = cvtpk(k[0], k[1]); ks.y = cvtpk(k[2], k[3]); ks.z = cvtpk(k[4], k[5]); ks.w = 0;
        *(uint4*)(Qb + ((size_t)bh*SS + s)*8) = qs;
        *(uint4*)(Kb + ((size_t)bh*SS + s)*8) = ks;
        // Vt swizzled scatter: rows d=0..5 = V^T, d=6 ones, d=7 zeros, d=8 ones
        ushort_t* vp = Vt + (size_t)bh*VT_PER_BH + kt*VT_PER_KT + m*VT_PER_M + hi*8 + j;
#pragma unroll
        for (int d = 0; d < HDD; ++d) vp[d*16] = f2bf(v[d]);
        vp[6*16] = 0x3F80u;   // 1.0
        vp[7*16] = 0;
        vp[8*16] = 0x3F80u;   // 1.0
    }
}

// ---------------- Kernel B: MFMA attention (unchanged) ----------------
__global__ __launch_bounds__(256) void attn_kernel(
    const ushort_t* __restrict__ Qb, const ushort_t* __restrict__ Kb,
    const ushort_t* __restrict__ Vt, float* __restrict__ Oa)
{
    int lane = threadIdx.x & 63;
    int wv   = threadIdx.x >> 6;
    int bh = blockIdx.x;
    int b = bh >> 2, h = bh & 3;
    int hi = lane >> 5;
    int c  = lane & 31;

    const ushort_t* Qp = Qb + (size_t)bh*SS*8;
    const ushort_t* Kp = Kb + (size_t)bh*SS*8;
    const ushort_t* Vp = Vt + (size_t)bh*VT_PER_BH + (c*2 + hi)*8;
    bool vld = (c < 9);

    f32x16 Z;
#pragma unroll
    for (int i = 0; i < 16; ++i) Z[i] = 0.f;

#pragma unroll
    for (int ti = 0; ti < 2; ++ti) {
        int tile = blockIdx.y*8 + wv*2 + ti;   // 0..15
        int q0 = tile * 32;
        uint4 qf = {0,0,0,0};
        if (hi == 0) qf = *(const uint4*)(Qp + ((size_t)(q0 + c))*8);
        bf16x8 bq = __builtin_bit_cast(bf16x8, qf);

        f32x16 O;
#pragma unroll
        for (int i = 0; i < 16; ++i) O[i] = 0.f;

#pragma unroll 2
        for (int kt = 0; kt < 16; ++kt) {
            uint4 kf = {0,0,0,0};
            if (hi == 0) kf = *(const uint4*)(Kp + ((size_t)(kt*32 + c))*8);
            f32x16 S = __builtin_amdgcn_mfma_f32_32x32x16_bf16(
                __builtin_bit_cast(bf16x8, kf), bq, Z, 0, 0, 0);
            uint4 fa, fb;
            fa.x = cvtpk(__builtin_amdgcn_exp2f(S[0]),  __builtin_amdgcn_exp2f(S[1]));
            fa.y = cvtpk(__builtin_amdgcn_exp2f(S[2]),  __builtin_amdgcn_exp2f(S[3]));
            fa.z = cvtpk(__builtin_amdgcn_exp2f(S[4]),  __builtin_amdgcn_exp2f(S[5]));
            fa.w = cvtpk(__builtin_amdgcn_exp2f(S[6]),  __builtin_amdgcn_exp2f(S[7]));
            fb.x = cvtpk(__builtin_amdgcn_exp2f(S[8]),  __builtin_amdgcn_exp2f(S[9]));
            fb.y = cvtpk(__builtin_amdgcn_exp2f(S[10]), __builtin_amdgcn_exp2f(S[11]));
            fb.z = cvtpk(__builtin_amdgcn_exp2f(S[12]), __builtin_amdgcn_exp2f(S[13]));
            fb.w = cvtpk(__builtin_amdgcn_exp2f(S[14]), __builtin_amdgcn_exp2f(S[15]));
            uint4 va = {0,0,0,0}, vb = {0,0,0,0};
            if (vld) {
                const ushort_t* vp = Vp + kt*VT_PER_KT;
                va = *(const uint4*)(vp);
                vb = *(const uint4*)(vp + VT_PER_M);
            }
            O = __builtin_amdgcn_mfma_f32_32x32x16_bf16(
                __builtin_bit_cast(bf16x8, va), __builtin_bit_cast(bf16x8, fa), O, 0, 0, 0);
            O = __builtin_amdgcn_mfma_f32_32x32x16_bf16(
                __builtin_bit_cast(bf16x8, vb), __builtin_bit_cast(bf16x8, fb), O, 0, 0, 0);
        }
        float inv = 1.0f / (hi ? O[2] : O[4]);
        float* op = Oa + ((size_t)b*SS + q0 + c)*DD + h*HDD;
        if (hi == 0) {
            *(float2*)(op + 0) = make_float2(O[0]*inv, O[1]*inv);
            *(float2*)(op + 2) = make_float2(O[2]*inv, O[3]*inv);
        } else {
            *(float2*)(op + 4) = make_float2(O[0]*inv, O[1]*inv);
        }
    }
}

// ------- Kernel C: out-proj + add&LN1 + FFN(2xrelu) + add&LN2 -------
__global__ __launch_bounds__(256, 1) void ffn_kernel(
    const float* __restrict__ x,  const float* __restrict__ Oa,
    const float* __restrict__ Wo, const float* __restrict__ W1,
    const float* __restrict__ W2,
    const float* __restrict__ g1, const float* __restrict__ b1,
    const float* __restrict__ g2, const float* __restrict__ b2,
    float* __restrict__ out)
{
    __shared__ float sWo[DD*DD], sW1[DFFN*DD], sW2[DD*DFFN];
    __shared__ float sg1[DD], sb1[DD], sg2[DD], sb2[DD];
    for (int i = threadIdx.x; i < DD*DD; i += 256) sWo[i] = Wo[i];
    for (int i = threadIdx.x; i < DFFN*DD; i += 256) sW1[i] = W1[i];
    for (int i = threadIdx.x; i < DD*DFFN; i += 256) sW2[i] = W2[i];
    if (threadIdx.x < DD) {
        sg1[threadIdx.x] = g1[threadIdx.x];
        sb1[threadIdx.x] = b1[threadIdx.x];
        sg2[threadIdx.x] = g2[threadIdx.x];
        sb2[threadIdx.x] = b2[threadIdx.x];
    }
    __syncthreads();

    int t = blockIdx.x * 256 + threadIdx.x;
    float xv[DD], ao[DD];
    const float4* xp = (const float4*)(x  + (size_t)t * DD);
    const float4* op = (const float4*)(Oa + (size_t)t * DD);
#pragma unroll
    for (int i = 0; i < DD/4; ++i) {
        float4 a = xp[i]; float4 c = op[i];
        xv[4*i+0]=a.x; xv[4*i+1]=a.y; xv[4*i+2]=a.z; xv[4*i+3]=a.w;
        ao[4*i+0]=c.x; ao[4*i+1]=c.y; ao[4*i+2]=c.z; ao[4*i+3]=c.w;
    }
    float x1[DD];
#pragma unroll
    for (int o = 0; o < DD; ++o) {
        float a = 0.f;
#pragma unroll
        for (int i = 0; i < DD; ++i) a = fmaf(ao[i], sWo[o*DD + i], a);
        x1[o] = a + xv[o];
    }
    {
        float mu = 0.f;
#pragma unroll
        for (int i = 0; i < DD; ++i) mu += x1[i];
        mu *= (1.0f/DD);
        float var = 0.f;
#pragma unroll
        for (int i = 0; i < DD; ++i) { float d = x1[i]-mu; var = fmaf(d,d,var); }
        var *= (1.0f/DD);
        float r = rsqrtf(var + EPSV);
#pragma unroll
        for (int i = 0; i < DD; ++i) x1[i] = (x1[i]-mu)*r*sg1[i] + sb1[i];
    }
    float hbuf[DFFN];
#pragma unroll
    for (int jj = 0; jj < DFFN; ++jj) {
        float a = 0.f;
#pragma unroll
        for (int i = 0; i < DD; ++i) a = fmaf(x1[i], sW1[jj*DD + i], a);
        hbuf[jj] = fmaxf(a, 0.f);
    }
    float f2[DD];
#pragma unroll
    for (int o = 0; o < DD; ++o) {
        float a = 0.f;
#pragma unroll
        for (int jj = 0; jj < DFFN; ++jj) a = fmaf(hbuf[jj], sW2[o*DFFN + jj], a);
        f2[o] = fmaxf(a, 0.f) + x1[o];
    }
    {
        float mu = 0.f;
#pragma unroll
        for (int i = 0; i < DD; ++i) mu += f2[i];
        mu *= (1.0f/DD);
        float var = 0.f;
#pragma unroll
        for (int i = 0; i < DD; ++i) { float d = f2[i]-mu; var = fmaf(d,d,var); }
        var *= (1.0f/DD);
        float r = rsqrtf(var + EPSV);
#pragma unroll
        for (int i = 0; i < DD; ++i) f2[i] = (f2[i]-mu)*r*sg2[i] + sb2[i];
    }
    float4* outp = (float4*)(out + (size_t)t * DD);
#pragma unroll
    for (int i = 0; i < DD/4; ++i)
        outp[i] = make_float4(f2[4*i+0], f2[4*i+1], f2[4*i+2], f2[4*i+3]);
}

extern "C" void kernel_launch(void* const* d_in, const int* in_sizes, int n_in,
                              void* d_out, int out_size, void* d_ws, size_t ws_size,
                              hipStream_t stream) {
    const float* x  = (const float*)d_in[0];
    const float* Wq = (const float*)d_in[1];
    const float* Wk = (const float*)d_in[2];
    const float* Wv = (const float*)d_in[3];
    const float* Wo = (const float*)d_in[4];
    const float* W1 = (const float*)d_in[5];
    const float* W2 = (const float*)d_in[6];
    const float* g1 = (const float*)d_in[7];
    const float* b1 = (const float*)d_in[8];
    const float* g2 = (const float*)d_in[9];
    const float* b2 = (const float*)d_in[10];
    float* out = (float*)d_out;

    size_t N8 = (size_t)NBH * SS * 8;         // Qb, Kb
    size_t NV = (size_t)NBH * VT_PER_BH;      // Vt
    ushort_t* Qb = (ushort_t*)d_ws;
    ushort_t* Kb = Qb + N8;
    ushort_t* Vt = Kb + N8;
    float*    Oa = (float*)(Vt + NV);

    qkv_kernel<<<NTOK/256, 256, 0, stream>>>(x, Wq, Wk, Wv, Qb, Kb, Vt);
    attn_kernel<<<dim3(NBH, 2), 256, 0, stream>>>(Qb, Kb, Vt, Oa);
    ffn_kernel<<<NTOK/256, 256, 0, stream>>>(x, Oa, Wo, W1, W2, g1, b1, g2, b2, out);
}

// Round 8
// 63.471 us; speedup vs baseline: 2.2608x; 1.3163x over previous
//
#include <hip/hip_runtime.h>

// Encoder block: B=128, S=512, D=24, H=4, HD=6, DFF=48, fp32 in/out.
// R8 (bisection): ffn = MFMA stage-1 (Wo GEMM + residual; attention-verified
// idioms only) -> LDS -> scalar LN1 -> scalar W1/W2 (2 threads/token) ->
// scalar LN2. Zero cross-lane exchanges; all handoffs via barriered LDS.
// qkv/attn unchanged (verified R3/R4/R5).

#define DD   24
#define HH   4
#define HDD  6
#define DFFN 48
#define SS   512
#define BB   128
#define NTOK (BB*SS)   // 65536
#define NBH  (BB*HH)   // 512

typedef unsigned short ushort_t;
typedef unsigned int   uint_t;
typedef __bf16  bf16x8  __attribute__((ext_vector_type(8)));
typedef float   f32x16  __attribute__((ext_vector_type(16)));

static constexpr float EPSV   = 1e-5f;
static constexpr float QSCALE = (float)(1.4426950408889634 / 2.449489742783178);

// Vt geometry: [bh][kt(16)][m(2)][d(9)][hi(2)][j(8)]  (ushort elements)
#define VT_PER_BH (16*2*9*2*8)   // 4608
#define VT_PER_KT (2*9*2*8)      // 576
#define VT_PER_M  (9*2*8)        // 144

__device__ __forceinline__ uint_t cvtpk(float lo, float hi) {
    uint_t r;
    asm("v_cvt_pk_bf16_f32 %0, %1, %2" : "=v"(r) : "v"(lo), "v"(hi));
    return r;
}
__device__ __forceinline__ ushort_t f2bf(float f) {
    return (ushort_t)cvtpk(f, 0.0f);
}

// ---------------- Kernel A: QKV projection -> bf16 Qb/Kb/Vt ----------------
__global__ __launch_bounds__(256, 1) void qkv_kernel(
    const float* __restrict__ x,  const float* __restrict__ Wq,
    const float* __restrict__ Wk, const float* __restrict__ Wv,
    ushort_t* __restrict__ Qb, ushort_t* __restrict__ Kb, ushort_t* __restrict__ Vt)
{
    __shared__ float sWq[DD*DD], sWk[DD*DD], sWv[DD*DD];
    for (int i = threadIdx.x; i < DD*DD; i += 256) {
        sWq[i] = Wq[i]; sWk[i] = Wk[i]; sWv[i] = Wv[i];
    }
    __syncthreads();

    int t = blockIdx.x * 256 + threadIdx.x;        // token id
    float xv[DD];
    const float4* xp = (const float4*)(x + (size_t)t * DD);
#pragma unroll
    for (int i = 0; i < DD/4; ++i) {
        float4 v = xp[i];
        xv[4*i+0] = v.x; xv[4*i+1] = v.y; xv[4*i+2] = v.z; xv[4*i+3] = v.w;
    }
    int b = t >> 9, s = t & 511;
    int kt  = s >> 5;
    int kl  = s & 31;
    int m   = (kl >> 4) & 1;
    int k16 = kl & 15;
    int hi  = (k16 >> 2) & 1;
    int j   = (k16 & 3) + ((k16 >> 3) << 2);
#pragma unroll
    for (int h = 0; h < HH; ++h) {
        float q[HDD], k[HDD], v[HDD];
#pragma unroll
        for (int d = 0; d < HDD; ++d) {
            int o = h*HDD + d;
            float aq = 0.f, ak = 0.f, av = 0.f;
#pragma unroll
            for (int i = 0; i < DD; ++i) {
                aq = fmaf(xv[i], sWq[o*DD + i], aq);
                ak = fmaf(xv[i], sWk[o*DD + i], ak);
                av = fmaf(xv[i], sWv[o*DD + i], av);
            }
            q[d] = aq * QSCALE; k[d] = ak; v[d] = av;
        }
        int bh = b*HH + h;
        uint4 qs, ks;
        qs.x = cvtpk(q[0], q[1]); qs.y = cvtpk(q[2], q[3]); qs.z = cvtpk(q[4], q[5]); qs.w = 0;
        ks.x = cvtpk(k[0], k[1]); ks.y = cvtpk(k[2], k[3]); ks.z = cvtpk(k[4], k[5]); ks.w = 0;
        *(uint4*)(Qb + ((size_t)bh*SS + s)*8) = qs;
        *(uint4*)(Kb + ((size_t)bh*SS + s)*8) = ks;
        ushort_t* vp = Vt + (size_t)bh*VT_PER_BH + kt*VT_PER_KT + m*VT_PER_M + hi*8 + j;
#pragma unroll
        for (int d = 0; d < HDD; ++d) vp[d*16] = f2bf(v[d]);
        vp[6*16] = 0x3F80u;   // 1.0
        vp[7*16] = 0;
        vp[8*16] = 0x3F80u;   // 1.0
    }
}

// ---------------- Kernel B: MFMA attention (unchanged) ----------------
__global__ __launch_bounds__(256) void attn_kernel(
    const ushort_t* __restrict__ Qb, const ushort_t* __restrict__ Kb,
    const ushort_t* __restrict__ Vt, float* __restrict__ Oa)
{
    int lane = threadIdx.x & 63;
    int wv   = threadIdx.x >> 6;
    int bh = blockIdx.x;
    int b = bh >> 2, h = bh & 3;
    int hi = lane >> 5;
    int c  = lane & 31;

    const ushort_t* Qp = Qb + (size_t)bh*SS*8;
    const ushort_t* Kp = Kb + (size_t)bh*SS*8;
    const ushort_t* Vp = Vt + (size_t)bh*VT_PER_BH + (c*2 + hi)*8;
    bool vld = (c < 9);

    f32x16 Z;
#pragma unroll
    for (int i = 0; i < 16; ++i) Z[i] = 0.f;

#pragma unroll
    for (int ti = 0; ti < 2; ++ti) {
        int tile = blockIdx.y*8 + wv*2 + ti;   // 0..15
        int q0 = tile * 32;
        uint4 qf = {0,0,0,0};
        if (hi == 0) qf = *(const uint4*)(Qp + ((size_t)(q0 + c))*8);
        bf16x8 bq = __builtin_bit_cast(bf16x8, qf);

        f32x16 O;
#pragma unroll
        for (int i = 0; i < 16; ++i) O[i] = 0.f;

#pragma unroll 2
        for (int kt = 0; kt < 16; ++kt) {
            uint4 kf = {0,0,0,0};
            if (hi == 0) kf = *(const uint4*)(Kp + ((size_t)(kt*32 + c))*8);
            f32x16 S = __builtin_amdgcn_mfma_f32_32x32x16_bf16(
                __builtin_bit_cast(bf16x8, kf), bq, Z, 0, 0, 0);
            uint4 fa, fb;
            fa.x = cvtpk(__builtin_amdgcn_exp2f(S[0]),  __builtin_amdgcn_exp2f(S[1]));
            fa.y = cvtpk(__builtin_amdgcn_exp2f(S[2]),  __builtin_amdgcn_exp2f(S[3]));
            fa.z = cvtpk(__builtin_amdgcn_exp2f(S[4]),  __builtin_amdgcn_exp2f(S[5]));
            fa.w = cvtpk(__builtin_amdgcn_exp2f(S[6]),  __builtin_amdgcn_exp2f(S[7]));
            fb.x = cvtpk(__builtin_amdgcn_exp2f(S[8]),  __builtin_amdgcn_exp2f(S[9]));
            fb.y = cvtpk(__builtin_amdgcn_exp2f(S[10]), __builtin_amdgcn_exp2f(S[11]));
            fb.z = cvtpk(__builtin_amdgcn_exp2f(S[12]), __builtin_amdgcn_exp2f(S[13]));
            fb.w = cvtpk(__builtin_amdgcn_exp2f(S[14]), __builtin_amdgcn_exp2f(S[15]));
            uint4 va = {0,0,0,0}, vb = {0,0,0,0};
            if (vld) {
                const ushort_t* vp = Vp + kt*VT_PER_KT;
                va = *(const uint4*)(vp);
                vb = *(const uint4*)(vp + VT_PER_M);
            }
            O = __builtin_amdgcn_mfma_f32_32x32x16_bf16(
                __builtin_bit_cast(bf16x8, va), __builtin_bit_cast(bf16x8, fa), O, 0, 0, 0);
            O = __builtin_amdgcn_mfma_f32_32x32x16_bf16(
                __builtin_bit_cast(bf16x8, vb), __builtin_bit_cast(bf16x8, fb), O, 0, 0, 0);
        }
        float inv = 1.0f / (hi ? O[2] : O[4]);
        float* op = Oa + ((size_t)b*SS + q0 + c)*DD + h*HDD;
        if (hi == 0) {
            *(float2*)(op + 0) = make_float2(O[0]*inv, O[1]*inv);
            *(float2*)(op + 2) = make_float2(O[2]*inv, O[3]*inv);
        } else {
            *(float2*)(op + 4) = make_float2(O[0]*inv, O[1]*inv);
        }
    }
}

// ------- Kernel C: ffn — MFMA stage1 + scalar LN1/W1/W2/LN2 via LDS -------
__device__ __forceinline__ void qload3(const float* row, int hi,
                                       float4& f0, float4& f1, float4& f2) {
    f0 = *(const float4*)(row + 4*hi);
    f1 = *(const float4*)(row + 8 + 4*hi);
    f2 = *(const float4*)(row + 16 + 4*hi);
}
__device__ __forceinline__ uint4 frag_kt0(float4 f0, float4 f1) {
    return make_uint4(cvtpk(f0.x,f0.y), cvtpk(f0.z,f0.w),
                      cvtpk(f1.x,f1.y), cvtpk(f1.z,f1.w));
}
__device__ __forceinline__ uint4 frag_kt1(float4 f2) {
    return make_uint4(cvtpk(f2.x,f2.y), cvtpk(f2.z,f2.w), 0u, 0u);
}
__device__ __forceinline__ bf16x8 asbf(uint4 u) { return __builtin_bit_cast(bf16x8, u); }

__global__ __launch_bounds__(256, 1) void ffn_kernel(
    const float* __restrict__ x,  const float* __restrict__ Oa,
    const float* __restrict__ Wo, const float* __restrict__ W1,
    const float* __restrict__ W2,
    const float* __restrict__ g1, const float* __restrict__ b1,
    const float* __restrict__ g2, const float* __restrict__ b2,
    float* __restrict__ out)
{
    __shared__ float sW1[DFFN*DD];      // row-major [48][24]
    __shared__ float sW2t[DFFN*DD];     // transposed: [j=48][o=24]
    __shared__ float sg1[DD], sb1[DD], sg2[DD], sb2[DD];
    __shared__ float xLDS[128][DD];     // stage1 out -> x1 (in-place LN1)
    __shared__ float FLDS[2][128][DD];  // W2 partial sums (per half)

    int tid = threadIdx.x;
    for (int i = tid; i < DFFN*DD; i += 256) {
        sW1[i] = W1[i];
        int jj = i / DD, o = i - jj*DD;
        sW2t[i] = W2[o*DFFN + jj];
    }
    if (tid < DD) {
        sg1[tid] = g1[tid]; sb1[tid] = b1[tid];
        sg2[tid] = g2[tid]; sb2[tid] = b2[tid];
    }

    int lane = tid & 63, wv = tid >> 6;
    int hi = lane >> 5, c = lane & 31;
    int tok = wv*32 + c;                    // block-local token 0..127
    int tc  = blockIdx.x*128 + tok;         // global token

    // ---- MFMA stage 1: Wo @ Oa + x residual (attention-verified idioms) ----
    float4 oa0, oa1, oa2, xr0, xr1, xr2;
    qload3(Oa + (size_t)tc*DD, hi, oa0, oa1, oa2);
    qload3(x  + (size_t)tc*DD, hi, xr0, xr1, xr2);
    uint4 aWo0 = {0,0,0,0}, aWo1 = {0,0,0,0};
    if (c < DD) {
        float4 w0,w1,w2;
        qload3(Wo + (size_t)c*DD, hi, w0,w1,w2);
        aWo0 = frag_kt0(w0,w1); aWo1 = frag_kt1(w2);
    }
    f32x16 Z;
#pragma unroll
    for (int i = 0; i < 16; ++i) Z[i] = 0.f;
    f32x16 C = __builtin_amdgcn_mfma_f32_32x32x16_bf16(asbf(aWo0), asbf(frag_kt0(oa0,oa1)), Z, 0,0,0);
    C = __builtin_amdgcn_mfma_f32_32x32x16_bf16(asbf(aWo1), asbf(frag_kt1(oa2)), C, 0,0,0);

    // write pre-LN rows: lane (c,hi) owns dims {0..3,8..11,16..19}+4hi of token tok
    *(float4*)&xLDS[tok][4*hi]      = make_float4(C[0]+xr0.x, C[1]+xr0.y, C[2]+xr0.z, C[3]+xr0.w);
    *(float4*)&xLDS[tok][8 + 4*hi]  = make_float4(C[4]+xr1.x, C[5]+xr1.y, C[6]+xr1.z, C[7]+xr1.w);
    *(float4*)&xLDS[tok][16 + 4*hi] = make_float4(C[8]+xr2.x, C[9]+xr2.y, C[10]+xr2.z, C[11]+xr2.w);
    __syncthreads();

    // ---- scalar LN1: one thread per token, in place ----
    if (tid < 128) {
        float v[DD], mu = 0.f;
#pragma unroll
        for (int i = 0; i < DD; ++i) { v[i] = xLDS[tid][i]; mu += v[i]; }
        mu *= (1.0f/DD);
        float vv = 0.f;
#pragma unroll
        for (int i = 0; i < DD; ++i) { float d = v[i]-mu; vv = fmaf(d,d,vv); }
        float rs = rsqrtf(vv*(1.0f/DD) + EPSV);
#pragma unroll
        for (int i = 0; i < DD; ++i) xLDS[tid][i] = (v[i]-mu)*rs*sg1[i] + sb1[i];
    }
    __syncthreads();

    // ---- scalar W1 (half of DFF) + W2 partials: 2 threads per token ----
    {
        int htok = tid & 127, half = tid >> 7;
        float xv[DD];
#pragma unroll
        for (int i = 0; i < DD; ++i) xv[i] = xLDS[htok][i];
        float fp[DD];
#pragma unroll
        for (int o = 0; o < DD; ++o) fp[o] = 0.f;
        for (int j = 0; j < DFFN/2; ++j) {
            int jj = half*(DFFN/2) + j;          // wave-uniform -> LDS broadcast
            const float* w1r = &sW1[jj*DD];
            float a = 0.f;
#pragma unroll
            for (int i = 0; i < DD; ++i) a = fmaf(xv[i], w1r[i], a);
            a = fmaxf(a, 0.f);                   // inner relu
            const float* w2r = &sW2t[jj*DD];
#pragma unroll
            for (int o = 0; o < DD; ++o) fp[o] = fmaf(a, w2r[o], fp[o]);
        }
#pragma unroll
        for (int o = 0; o < DD; ++o) FLDS[half][htok][o] = fp[o];
    }
    __syncthreads();

    // ---- scalar LN2 + store: one thread per token ----
    if (tid < 128) {
        float f2[DD], mu = 0.f;
#pragma unroll
        for (int o = 0; o < DD; ++o) {
            float fo = fmaxf(FLDS[0][tid][o] + FLDS[1][tid][o], 0.f) + xLDS[tid][o];
            f2[o] = fo; mu += fo;
        }
        mu *= (1.0f/DD);
        float vv = 0.f;
#pragma unroll
        for (int o = 0; o < DD; ++o) { float d = f2[o]-mu; vv = fmaf(d,d,vv); }
        float rs = rsqrtf(vv*(1.0f/DD) + EPSV);
        float ov[DD];
#pragma unroll
        for (int o = 0; o < DD; ++o) ov[o] = (f2[o]-mu)*rs*sg2[o] + sb2[o];
        float4* op = (float4*)(out + ((size_t)blockIdx.x*128 + tid)*DD);
#pragma unroll
        for (int i = 0; i < DD/4; ++i)
            op[i] = make_float4(ov[4*i+0], ov[4*i+1], ov[4*i+2], ov[4*i+3]);
    }
}

extern "C" void kernel_launch(void* const* d_in, const int* in_sizes, int n_in,
                              void* d_out, int out_size, void* d_ws, size_t ws_size,
                              hipStream_t stream) {
    const float* x  = (const float*)d_in[0];
    const float* Wq = (const float*)d_in[1];
    const float* Wk = (const float*)d_in[2];
    const float* Wv = (const float*)d_in[3];
    const float* Wo = (const float*)d_in[4];
    const float* W1 = (const float*)d_in[5];
    const float* W2 = (const float*)d_in[6];
    const float* g1 = (const float*)d_in[7];
    const float* b1 = (const float*)d_in[8];
    const float* g2 = (const float*)d_in[9];
    const float* b2 = (const float*)d_in[10];
    float* out = (float*)d_out;

    size_t N8 = (size_t)NBH * SS * 8;         // Qb, Kb
    size_t NV = (size_t)NBH * VT_PER_BH;      // Vt
    ushort_t* Qb = (ushort_t*)d_ws;
    ushort_t* Kb = Qb + N8;
    ushort_t* Vt = Kb + N8;
    float*    Oa = (float*)(Vt + NV);

    qkv_kernel<<<NTOK/256, 256, 0, stream>>>(x, Wq, Wk, Wv, Qb, Kb, Vt);
    attn_kernel<<<dim3(NBH, 2), 256, 0, stream>>>(Qb, Kb, Vt, Oa);
    ffn_kernel<<<NTOK/128, 256, 0, stream>>>(x, Oa, Wo, W1, W2, g1, b1, g2, b2, out);
}

// Round 10
// 58.935 us; speedup vs baseline: 2.4349x; 1.0770x over previous
//
#include <hip/hip_runtime.h>

// Encoder block: B=128, S=512, D=24, H=4, HD=6, DFF=48, fp32 in/out.
// R10 = R8 (proven: MFMA stage-1 + scalar LN/W1/W2 ffn) with ONE change:
// qkv = one thread per (token,head) -> 4 waves/SIMD (was 1). Math-identical
// FMAs and addresses to R8's qkv; pure TLP change.
// attn: MFMA 32x32x16, zero-LDS (verified R3..R9).

#define DD   24
#define HH   4
#define HDD  6
#define DFFN 48
#define SS   512
#define BB   128
#define NTOK (BB*SS)   // 65536
#define NBH  (BB*HH)   // 512

typedef unsigned short ushort_t;
typedef unsigned int   uint_t;
typedef __bf16  bf16x8  __attribute__((ext_vector_type(8)));
typedef float   f32x16  __attribute__((ext_vector_type(16)));

static constexpr float EPSV   = 1e-5f;
static constexpr float QSCALE = (float)(1.4426950408889634 / 2.449489742783178);

// Vt geometry: [bh][kt(16)][m(2)][d(9)][hi(2)][j(8)]  (ushort elements)
#define VT_PER_BH (16*2*9*2*8)   // 4608
#define VT_PER_KT (2*9*2*8)      // 576
#define VT_PER_M  (9*2*8)        // 144

__device__ __forceinline__ uint_t cvtpk(float lo, float hi) {
    uint_t r;
    asm("v_cvt_pk_bf16_f32 %0, %1, %2" : "=v"(r) : "v"(lo), "v"(hi));
    return r;
}
__device__ __forceinline__ ushort_t f2bf(float f) {
    return (ushort_t)cvtpk(f, 0.0f);
}

// ---------------- Kernel A: QKV projection, one thread per (token, head) ----
__global__ __launch_bounds__(256, 4) void qkv_kernel(
    const float* __restrict__ x,  const float* __restrict__ Wq,
    const float* __restrict__ Wk, const float* __restrict__ Wv,
    ushort_t* __restrict__ Qb, ushort_t* __restrict__ Kb, ushort_t* __restrict__ Vt)
{
    __shared__ float sWq[DD*DD], sWk[DD*DD], sWv[DD*DD];
    for (int i = threadIdx.x; i < DD*DD; i += 256) {
        sWq[i] = Wq[i]; sWk[i] = Wk[i]; sWv[i] = Wv[i];
    }
    __syncthreads();

    int g = blockIdx.x * 256 + threadIdx.x;
    int t = g >> 2, h = g & 3;                 // token, head
    float xv[DD];
    const float4* xp = (const float4*)(x + (size_t)t * DD);
#pragma unroll
    for (int i = 0; i < DD/4; ++i) {
        float4 v = xp[i];
        xv[4*i+0] = v.x; xv[4*i+1] = v.y; xv[4*i+2] = v.z; xv[4*i+3] = v.w;
    }
    int b = t >> 9, s = t & 511;
    int kt  = s >> 5;
    int kl  = s & 31;
    int m   = (kl >> 4) & 1;
    int k16 = kl & 15;
    int hi  = (k16 >> 2) & 1;
    int j   = (k16 & 3) + ((k16 >> 3) << 2);

    float q[HDD], k[HDD], v[HDD];
#pragma unroll
    for (int d = 0; d < HDD; ++d) {
        int o = h*HDD + d;
        float aq = 0.f, ak = 0.f, av = 0.f;
#pragma unroll
        for (int i = 0; i < DD; ++i) {
            aq = fmaf(xv[i], sWq[o*DD + i], aq);
            ak = fmaf(xv[i], sWk[o*DD + i], ak);
            av = fmaf(xv[i], sWv[o*DD + i], av);
        }
        q[d] = aq * QSCALE; k[d] = ak; v[d] = av;
    }
    int bh = b*HH + h;
    uint4 qs, ks;
    qs.x = cvtpk(q[0], q[1]); qs.y = cvtpk(q[2], q[3]); qs.z = cvtpk(q[4], q[5]); qs.w = 0;
    ks.x = cvtpk(k[0], k[1]); ks.y = cvtpk(k[2], k[3]); ks.z = cvtpk(k[4], k[5]); ks.w = 0;
    *(uint4*)(Qb + ((size_t)bh*SS + s)*8) = qs;
    *(uint4*)(Kb + ((size_t)bh*SS + s)*8) = ks;
    ushort_t* vp = Vt + (size_t)bh*VT_PER_BH + kt*VT_PER_KT + m*VT_PER_M + hi*8 + j;
#pragma unroll
    for (int d = 0; d < HDD; ++d) vp[d*16] = f2bf(v[d]);
    vp[6*16] = 0x3F80u;   // 1.0
    vp[7*16] = 0;
    vp[8*16] = 0x3F80u;   // 1.0
}

// ---------------- Kernel B: MFMA attention (unchanged, verified) ----------------
__global__ __launch_bounds__(256) void attn_kernel(
    const ushort_t* __restrict__ Qb, const ushort_t* __restrict__ Kb,
    const ushort_t* __restrict__ Vt, float* __restrict__ Oa)
{
    int lane = threadIdx.x & 63;
    int wv   = threadIdx.x >> 6;
    int bh = blockIdx.x;
    int b = bh >> 2, h = bh & 3;
    int hi = lane >> 5;
    int c  = lane & 31;

    const ushort_t* Qp = Qb + (size_t)bh*SS*8;
    const ushort_t* Kp = Kb + (size_t)bh*SS*8;
    const ushort_t* Vp = Vt + (size_t)bh*VT_PER_BH + (c*2 + hi)*8;
    bool vld = (c < 9);

    f32x16 Z;
#pragma unroll
    for (int i = 0; i < 16; ++i) Z[i] = 0.f;

#pragma unroll
    for (int ti = 0; ti < 2; ++ti) {
        int tile = blockIdx.y*8 + wv*2 + ti;   // 0..15
        int q0 = tile * 32;
        uint4 qf = {0,0,0,0};
        if (hi == 0) qf = *(const uint4*)(Qp + ((size_t)(q0 + c))*8);
        bf16x8 bq = __builtin_bit_cast(bf16x8, qf);

        f32x16 O;
#pragma unroll
        for (int i = 0; i < 16; ++i) O[i] = 0.f;

#pragma unroll 2
        for (int kt = 0; kt < 16; ++kt) {
            uint4 kf = {0,0,0,0};
            if (hi == 0) kf = *(const uint4*)(Kp + ((size_t)(kt*32 + c))*8);
            f32x16 S = __builtin_amdgcn_mfma_f32_32x32x16_bf16(
                __builtin_bit_cast(bf16x8, kf), bq, Z, 0, 0, 0);
            uint4 fa, fb;
            fa.x = cvtpk(__builtin_amdgcn_exp2f(S[0]),  __builtin_amdgcn_exp2f(S[1]));
            fa.y = cvtpk(__builtin_amdgcn_exp2f(S[2]),  __builtin_amdgcn_exp2f(S[3]));
            fa.z = cvtpk(__builtin_amdgcn_exp2f(S[4]),  __builtin_amdgcn_exp2f(S[5]));
            fa.w = cvtpk(__builtin_amdgcn_exp2f(S[6]),  __builtin_amdgcn_exp2f(S[7]));
            fb.x = cvtpk(__builtin_amdgcn_exp2f(S[8]),  __builtin_amdgcn_exp2f(S[9]));
            fb.y = cvtpk(__builtin_amdgcn_exp2f(S[10]), __builtin_amdgcn_exp2f(S[11]));
            fb.z = cvtpk(__builtin_amdgcn_exp2f(S[12]), __builtin_amdgcn_exp2f(S[13]));
            fb.w = cvtpk(__builtin_amdgcn_exp2f(S[14]), __builtin_amdgcn_exp2f(S[15]));
            uint4 va = {0,0,0,0}, vb = {0,0,0,0};
            if (vld) {
                const ushort_t* vp = Vp + kt*VT_PER_KT;
                va = *(const uint4*)(vp);
                vb = *(const uint4*)(vp + VT_PER_M);
            }
            O = __builtin_amdgcn_mfma_f32_32x32x16_bf16(
                __builtin_bit_cast(bf16x8, va), __builtin_bit_cast(bf16x8, fa), O, 0, 0, 0);
            O = __builtin_amdgcn_mfma_f32_32x32x16_bf16(
                __builtin_bit_cast(bf16x8, vb), __builtin_bit_cast(bf16x8, fb), O, 0, 0, 0);
        }
        float inv = 1.0f / (hi ? O[2] : O[4]);
        float* op = Oa + ((size_t)b*SS + q0 + c)*DD + h*HDD;
        if (hi == 0) {
            *(float2*)(op + 0) = make_float2(O[0]*inv, O[1]*inv);
            *(float2*)(op + 2) = make_float2(O[2]*inv, O[3]*inv);
        } else {
            *(float2*)(op + 4) = make_float2(O[0]*inv, O[1]*inv);
        }
    }
}

// ------- Kernel C (R8-proven): MFMA stage1 + scalar LN1/W1/W2/LN2 via LDS -------
__device__ __forceinline__ void qload3(const float* row, int hi,
                                       float4& f0, float4& f1, float4& f2) {
    f0 = *(const float4*)(row + 4*hi);
    f1 = *(const float4*)(row + 8 + 4*hi);
    f2 = *(const float4*)(row + 16 + 4*hi);
}
__device__ __forceinline__ uint4 frag_kt0(float4 f0, float4 f1) {
    return make_uint4(cvtpk(f0.x,f0.y), cvtpk(f0.z,f0.w),
                      cvtpk(f1.x,f1.y), cvtpk(f1.z,f1.w));
}
__device__ __forceinline__ uint4 frag_kt1(float4 f2) {
    return make_uint4(cvtpk(f2.x,f2.y), cvtpk(f2.z,f2.w), 0u, 0u);
}
__device__ __forceinline__ bf16x8 asbf(uint4 u) { return __builtin_bit_cast(bf16x8, u); }

__global__ __launch_bounds__(256, 1) void ffn_kernel(
    const float* __restrict__ x,  const float* __restrict__ Oa,
    const float* __restrict__ Wo, const float* __restrict__ W1,
    const float* __restrict__ W2,
    const float* __restrict__ g1, const float* __restrict__ b1,
    const float* __restrict__ g2, const float* __restrict__ b2,
    float* __restrict__ out)
{
    __shared__ float sW1[DFFN*DD];      // row-major [48][24]
    __shared__ float sW2t[DFFN*DD];     // transposed: [j=48][o=24]
    __shared__ float sg1[DD], sb1[DD], sg2[DD], sb2[DD];
    __shared__ float xLDS[128][DD];     // stage1 out -> x1 (in-place LN1)
    __shared__ float FLDS[2][128][DD];  // W2 partial sums (per half)

    int tid = threadIdx.x;
    for (int i = tid; i < DFFN*DD; i += 256) {
        sW1[i] = W1[i];
        int jj = i / DD, o = i - jj*DD;
        sW2t[i] = W2[o*DFFN + jj];
    }
    if (tid < DD) {
        sg1[tid] = g1[tid]; sb1[tid] = b1[tid];
        sg2[tid] = g2[tid]; sb2[tid] = b2[tid];
    }

    int lane = tid & 63, wv = tid >> 6;
    int hi = lane >> 5, c = lane & 31;
    int tok = wv*32 + c;                    // block-local token 0..127
    int tc  = blockIdx.x*128 + tok;         // global token

    // ---- MFMA stage 1: Wo @ Oa + x residual ----
    float4 oa0, oa1, oa2, xr0, xr1, xr2;
    qload3(Oa + (size_t)tc*DD, hi, oa0, oa1, oa2);
    qload3(x  + (size_t)tc*DD, hi, xr0, xr1, xr2);
    uint4 aWo0 = {0,0,0,0}, aWo1 = {0,0,0,0};
    if (c < DD) {
        float4 w0,w1,w2;
        qload3(Wo + (size_t)c*DD, hi, w0,w1,w2);
        aWo0 = frag_kt0(w0,w1); aWo1 = frag_kt1(w2);
    }
    f32x16 Z;
#pragma unroll
    for (int i = 0; i < 16; ++i) Z[i] = 0.f;
    f32x16 C = __builtin_amdgcn_mfma_f32_32x32x16_bf16(asbf(aWo0), asbf(frag_kt0(oa0,oa1)), Z, 0,0,0);
    C = __builtin_amdgcn_mfma_f32_32x32x16_bf16(asbf(aWo1), asbf(frag_kt1(oa2)), C, 0,0,0);

    // write pre-LN rows: lane (c,hi) owns dims {0..3,8..11,16..19}+4hi of token tok
    *(float4*)&xLDS[tok][4*hi]      = make_float4(C[0]+xr0.x, C[1]+xr0.y, C[2]+xr0.z, C[3]+xr0.w);
    *(float4*)&xLDS[tok][8 + 4*hi]  = make_float4(C[4]+xr1.x, C[5]+xr1.y, C[6]+xr1.z, C[7]+xr1.w);
    *(float4*)&xLDS[tok][16 + 4*hi] = make_float4(C[8]+xr2.x, C[9]+xr2.y, C[10]+xr2.z, C[11]+xr2.w);
    __syncthreads();

    // ---- scalar LN1: one thread per token, in place ----
    if (tid < 128) {
        float v[DD], mu = 0.f;
#pragma unroll
        for (int i = 0; i < DD; ++i) { v[i] = xLDS[tid][i]; mu += v[i]; }
        mu *= (1.0f/DD);
        float vv = 0.f;
#pragma unroll
        for (int i = 0; i < DD; ++i) { float d = v[i]-mu; vv = fmaf(d,d,vv); }
        float rs = rsqrtf(vv*(1.0f/DD) + EPSV);
#pragma unroll
        for (int i = 0; i < DD; ++i) xLDS[tid][i] = (v[i]-mu)*rs*sg1[i] + sb1[i];
    }
    __syncthreads();

    // ---- scalar W1 (half of DFF) + W2 partials: 2 threads per token ----
    {
        int htok = tid & 127, half = tid >> 7;
        float xv[DD];
#pragma unroll
        for (int i = 0; i < DD; ++i) xv[i] = xLDS[htok][i];
        float fp[DD];
#pragma unroll
        for (int o = 0; o < DD; ++o) fp[o] = 0.f;
        for (int j = 0; j < DFFN/2; ++j) {
            int jj = half*(DFFN/2) + j;          // wave-uniform -> LDS broadcast
            const float* w1r = &sW1[jj*DD];
            float a = 0.f;
#pragma unroll
            for (int i = 0; i < DD; ++i) a = fmaf(xv[i], w1r[i], a);
            a = fmaxf(a, 0.f);                   // inner relu
            const float* w2r = &sW2t[jj*DD];
#pragma unroll
            for (int o = 0; o < DD; ++o) fp[o] = fmaf(a, w2r[o], fp[o]);
        }
#pragma unroll
        for (int o = 0; o < DD; ++o) FLDS[half][htok][o] = fp[o];
    }
    __syncthreads();

    // ---- scalar LN2 + store: one thread per token ----
    if (tid < 128) {
        float f2[DD], mu = 0.f;
#pragma unroll
        for (int o = 0; o < DD; ++o) {
            float fo = fmaxf(FLDS[0][tid][o] + FLDS[1][tid][o], 0.f) + xLDS[tid][o];
            f2[o] = fo; mu += fo;
        }
        mu *= (1.0f/DD);
        float vv = 0.f;
#pragma unroll
        for (int o = 0; o < DD; ++o) { float d = f2[o]-mu; vv = fmaf(d,d,vv); }
        float rs = rsqrtf(vv*(1.0f/DD) + EPSV);
        float ov[DD];
#pragma unroll
        for (int o = 0; o < DD; ++o) ov[o] = (f2[o]-mu)*rs*sg2[o] + sb2[o];
        float4* op = (float4*)(out + ((size_t)blockIdx.x*128 + tid)*DD);
#pragma unroll
        for (int i = 0; i < DD/4; ++i)
            op[i] = make_float4(ov[4*i+0], ov[4*i+1], ov[4*i+2], ov[4*i+3]);
    }
}

extern "C" void kernel_launch(void* const* d_in, const int* in_sizes, int n_in,
                              void* d_out, int out_size, void* d_ws, size_t ws_size,
                              hipStream_t stream) {
    const float* x  = (const float*)d_in[0];
    const float* Wq = (const float*)d_in[1];
    const float* Wk = (const float*)d_in[2];
    const float* Wv = (const float*)d_in[3];
    const float* Wo = (const float*)d_in[4];
    const float* W1 = (const float*)d_in[5];
    const float* W2 = (const float*)d_in[6];
    const float* g1 = (const float*)d_in[7];
    const float* b1 = (const float*)d_in[8];
    const float* g2 = (const float*)d_in[9];
    const float* b2 = (const float*)d_in[10];
    float* out = (float*)d_out;

    size_t N8 = (size_t)NBH * SS * 8;         // Qb, Kb
    size_t NV = (size_t)NBH * VT_PER_BH;      // Vt
    ushort_t* Qb = (ushort_t*)d_ws;
    ushort_t* Kb = Qb + N8;
    ushort_t* Vt = Kb + N8;
    float*    Oa = (float*)(Vt + NV);

    qkv_kernel<<<NTOK*4/256, 256, 0, stream>>>(x, Wq, Wk, Wv, Qb, Kb, Vt);
    attn_kernel<<<dim3(NBH, 2), 256, 0, stream>>>(Qb, Kb, Vt, Oa);
    ffn_kernel<<<NTOK/128, 256, 0, stream>>>(x, Oa, Wo, W1, W2, g1, b1, g2, b2, out);
}